// Round 13
// baseline (165.356 us; speedup 1.0000x reference)
//
#include <hip/hip_runtime.h>

// ---------------------------------------------------------------------------
// GCN link-prediction pipeline, R13 (= R12 with grid-occupancy fix for the
// two gather kernels: 32 nodes/block -> 2x grid -> 8 blocks/CU resident;
// conv1 MFMA remapped to keep all 4 waves busy; scan2 folded into scan3).
//   fused01:     xw1 = bf16( (x @ W_init + b_init) @ W1 )
//   conv1_fused: xw2 = bf16( relu(gather(xw1)+self+b1) @ W2 )  [r1 in LDS]
//   gath2_flat:  h2 = bf16(gather(xw2)+self+b2)
//   score:       logits[e] = dot(h2[ea], h2[eb])
// ---------------------------------------------------------------------------

typedef __attribute__((ext_vector_type(8))) short short8;
typedef __attribute__((ext_vector_type(4))) float f32x4;

__device__ __forceinline__ ushort f2bf(float v) {
    unsigned u = __float_as_uint(v);
    return (ushort)((u + 0x7FFFu + ((u >> 16) & 1u)) >> 16);
}
__device__ __forceinline__ float bf2f(ushort b) {
    return __uint_as_float(((unsigned)b) << 16);
}
__device__ __forceinline__ float bflo(unsigned u) { return __uint_as_float(u << 16); }
__device__ __forceinline__ float bfhi(unsigned u) { return __uint_as_float(u & 0xFFFF0000u); }
__device__ __forceinline__ unsigned packbf(float x, float y) {
    return (unsigned)f2bf(x) | ((unsigned)f2bf(y) << 16);
}
__device__ __forceinline__ void split2(float v, ushort& h, ushort& l) {
    unsigned u = __float_as_uint(v);
    unsigned hb = (u + 0x7FFFu + ((u >> 16) & 1u)) & 0xFFFF0000u;
    h = (ushort)(hb >> 16);
    l = f2bf(v - __uint_as_float(hb));
}

// ---------------- prep: zero counts/cursor + all weight transposes ----------
__global__ void prep_kernel(const float* __restrict__ Wi, const float* __restrict__ W1,
                            const float* __restrict__ W2,
                            ushort* __restrict__ Ti, ushort* __restrict__ T1,
                            ushort* __restrict__ T2, int* __restrict__ zp, int ztot)
{
    int o = blockIdx.x * blockDim.x + threadIdx.x;
    if (o < ztot) zp[o] = 0;
    if (o < 16384) {
        int c = o >> 7, k = o & 127;
        Ti[o] = f2bf(Wi[(size_t)k * 128 + c]);
    } else if (o < 32768) {
        int p = o - 16384;
        int c = p >> 7, k = p & 127;
        T1[p] = f2bf(W1[(size_t)k * 128 + c]);
    } else if (o < 40960) {
        int p = o - 32768;
        int c = p >> 7, k = p & 127;
        T2[p] = f2bf(W2[(size_t)k * 64 + c]);
    }
}

// ---------------- CSR build ----------------
__global__ void hist_kernel(const int* __restrict__ tgt, int* __restrict__ counts, int e) {
    int i = blockIdx.x * blockDim.x + threadIdx.x;
    if (i < e) atomicAdd(&counts[tgt[i]], 1);
}
__global__ __launch_bounds__(256)
void scan1_kernel(const int* __restrict__ counts, int* __restrict__ rowptr,
                  int* __restrict__ bsum, float* __restrict__ dinv, int n)
{
    __shared__ int sdata[256];
    const int t = threadIdx.x;
    const int base = blockIdx.x * 1024 + t * 4;
    int v[4];
#pragma unroll
    for (int i = 0; i < 4; i++) v[i] = (base + i < n) ? counts[base + i] : 0;
#pragma unroll
    for (int i = 0; i < 4; i++)
        if (base + i < n) dinv[base + i] = 1.0f / sqrtf((float)(v[i] + 1));
    int tsum = v[0] + v[1] + v[2] + v[3];
    sdata[t] = tsum;
    __syncthreads();
    for (int off = 1; off < 256; off <<= 1) {
        int x = (t >= off) ? sdata[t - off] : 0;
        __syncthreads();
        if (t >= off) sdata[t] += x;
        __syncthreads();
    }
    if (t == 255) bsum[blockIdx.x] = sdata[255];
    int run = sdata[t] - tsum;
#pragma unroll
    for (int i = 0; i < 4; i++) {
        if (base + i < n) rowptr[base + i] = run;
        run += v[i];
    }
}
// scan3 (absorbs scan2): each 256-wide block lies inside one 1024-chunk, so
// its bsum prefix is a single scalar; thread 0 computes it (nb <= 98).
__global__ void scan3_kernel(int* __restrict__ rowptr, const int* __restrict__ bsum,
                             int n, int e_total, int nb)
{
    __shared__ int pre;
    const int k0 = (blockIdx.x * 256) >> 10;
    if (threadIdx.x == 0) {
        int s = 0;
        for (int k = 0; k < k0; ++k) s += bsum[k];
        pre = s;
    }
    __syncthreads();
    int i = blockIdx.x * 256 + threadIdx.x;
    if (i < n) rowptr[i] += pre;
    if (i == 0) rowptr[n] = e_total;
}
__global__ void scatter_kernel(const int* __restrict__ src, const int* __restrict__ tgt,
                               const float* __restrict__ dinv, const int* __restrict__ rowptr,
                               int* __restrict__ cursor, int2* __restrict__ ew, int e)
{
    int i = blockIdx.x * blockDim.x + threadIdx.x;
    if (i >= e) return;
    int s = src[i], t = tgt[i];
    int p = rowptr[t] + atomicAdd(&cursor[t], 1);
    ew[p] = make_int2(s, __float_as_int(dinv[s] * dinv[t]));
}

// ---------------------------------------------------------------------------
// Fused gemm0+gemm1 (unchanged from R11): xw1 = bf16((x @ Wi + bi) @ W1).
// ---------------------------------------------------------------------------
__global__ __launch_bounds__(256)
void fused_gemm01_kernel(const float* __restrict__ x,
                         const ushort* __restrict__ WTi, const ushort* __restrict__ WT1,
                         const float* __restrict__ bias, ushort* __restrict__ xw1, int M)
{
    __shared__ ushort raw[20480];                            // 40 KiB
    ushort (*H0)[128][8] = (ushort(*)[128][8])raw;           // 16 ks, 32 KiB
    ushort (*Ah)[128][8] = (ushort(*)[128][8])raw;           // aliases H0[0..4)
    ushort (*Al)[128][8] = (ushort(*)[128][8])(raw + 4096);  // aliases H0[4..8)
    ushort (*Bs)[128][8] = (ushort(*)[128][8])(raw + 16384); // 8 KiB

    const int tid = threadIdx.x;
    const int row0 = blockIdx.x * 128;
    const int wv = tid >> 6;
    const int l  = tid & 63;
    const int lr = l & 15;
    const int lk = l >> 4;

    f32x4 acc0[8], acc1[8];
#pragma unroll
    for (int n = 0; n < 8; ++n) {
        acc0[n] = (f32x4){0.f, 0.f, 0.f, 0.f};
        acc1[n] = (f32x4){0.f, 0.f, 0.f, 0.f};
    }

    for (int kk = 0; kk < 128; kk += 32) {
        {
            const int r  = tid >> 1;
            const int kh = tid & 1;
            const int gr = row0 + r;
            float f[16];
            if (gr < M) {
                const float4* p = (const float4*)(x + (size_t)gr * 128 + kk + kh * 16);
                float4 q0 = p[0], q1 = p[1], q2 = p[2], q3 = p[3];
                f[0]=q0.x; f[1]=q0.y; f[2]=q0.z; f[3]=q0.w;
                f[4]=q1.x; f[5]=q1.y; f[6]=q1.z; f[7]=q1.w;
                f[8]=q2.x; f[9]=q2.y; f[10]=q2.z; f[11]=q2.w;
                f[12]=q3.x; f[13]=q3.y; f[14]=q3.z; f[15]=q3.w;
            } else {
#pragma unroll
                for (int j = 0; j < 16; j++) f[j] = 0.f;
            }
#pragma unroll
            for (int uu = 0; uu < 2; ++uu) {
                short8 hv, lv;
#pragma unroll
                for (int j = 0; j < 8; ++j) {
                    ushort h, lo;
                    split2(f[8 * uu + j], h, lo);
                    hv[j] = (short)h; lv[j] = (short)lo;
                }
                *(short8*)&Ah[2 * kh + uu][r][0] = hv;
                *(short8*)&Al[2 * kh + uu][r][0] = lv;
            }
        }
        {
#pragma unroll
            for (int u = 0; u < 2; ++u) {
                const int unit = tid * 2 + u;
                const int c   = unit >> 2;
                const int kgl = unit & 3;
                *(short8*)&Bs[kgl][c][0] = *(const short8*)(WTi + (size_t)c * 128 + kk + 8 * kgl);
            }
        }
        __syncthreads();
        short8 ah0 = *(const short8*)&Ah[lk][wv * 32 + lr][0];
        short8 ah1 = *(const short8*)&Ah[lk][wv * 32 + 16 + lr][0];
        short8 al0 = *(const short8*)&Al[lk][wv * 32 + lr][0];
        short8 al1 = *(const short8*)&Al[lk][wv * 32 + 16 + lr][0];
#pragma unroll
        for (int n = 0; n < 8; ++n) {
            short8 bh = *(const short8*)&Bs[lk][n * 16 + lr][0];
            acc0[n] = __builtin_amdgcn_mfma_f32_16x16x32_bf16(bh, ah0, acc0[n], 0, 0, 0);
            acc1[n] = __builtin_amdgcn_mfma_f32_16x16x32_bf16(bh, ah1, acc1[n], 0, 0, 0);
            acc0[n] = __builtin_amdgcn_mfma_f32_16x16x32_bf16(bh, al0, acc0[n], 0, 0, 0);
            acc1[n] = __builtin_amdgcn_mfma_f32_16x16x32_bf16(bh, al1, acc1[n], 0, 0, 0);
        }
        __syncthreads();
    }

#pragma unroll
    for (int n = 0; n < 8; ++n) {
        const float4 b4 = *(const float4*)(bias + n * 16 + 4 * lk);
        const float bb[4] = {b4.x, b4.y, b4.z, b4.w};
        const int ks = 2 * n + (lk >> 1);
        const int jo = (lk & 1) * 4;
#pragma unroll
        for (int half = 0; half < 2; ++half) {
            const int m = wv * 32 + 16 * half + lr;
            unsigned hw[4];
#pragma unroll
            for (int r = 0; r < 4; ++r)
                hw[r] = f2bf((half ? acc1[n][r] : acc0[n][r]) + bb[r]);
            uint2 uh;
            uh.x = hw[0] | (hw[1] << 16);
            uh.y = hw[2] | (hw[3] << 16);
            *(uint2*)&H0[ks][m][jo] = uh;
        }
    }
    __syncthreads();

#pragma unroll
    for (int n = 0; n < 8; ++n) {
        acc0[n] = (f32x4){0.f, 0.f, 0.f, 0.f};
        acc1[n] = (f32x4){0.f, 0.f, 0.f, 0.f};
    }
    for (int kk = 0; kk < 4; ++kk) {
        {
#pragma unroll
            for (int u = 0; u < 2; ++u) {
                const int unit = tid * 2 + u;
                const int c   = unit >> 2;
                const int kgl = unit & 3;
                *(short8*)&Bs[kgl][c][0] = *(const short8*)(WT1 + (size_t)c * 128 + kk * 32 + 8 * kgl);
            }
        }
        __syncthreads();
        short8 a0 = *(const short8*)&H0[kk * 4 + lk][wv * 32 + lr][0];
        short8 a1 = *(const short8*)&H0[kk * 4 + lk][wv * 32 + 16 + lr][0];
#pragma unroll
        for (int n = 0; n < 8; ++n) {
            short8 bh = *(const short8*)&Bs[lk][n * 16 + lr][0];
            acc0[n] = __builtin_amdgcn_mfma_f32_16x16x32_bf16(bh, a0, acc0[n], 0, 0, 0);
            acc1[n] = __builtin_amdgcn_mfma_f32_16x16x32_bf16(bh, a1, acc1[n], 0, 0, 0);
        }
        __syncthreads();
    }

#pragma unroll
    for (int n = 0; n < 8; ++n) {
#pragma unroll
        for (int half = 0; half < 2; ++half) {
            const int m = row0 + wv * 32 + 16 * half + lr;
            if (m < M) {
                uint2 u;
                const f32x4 a = half ? acc1[n] : acc0[n];
                u.x = (unsigned)f2bf(a[0]) | ((unsigned)f2bf(a[1]) << 16);
                u.y = (unsigned)f2bf(a[2]) | ((unsigned)f2bf(a[3]) << 16);
                *(uint2*)(xw1 + (size_t)m * 128 + n * 16 + 4 * lk) = u;
            }
        }
    }
}

// ---------------------------------------------------------------------------
// conv1_fused v4: 32 nodes/block (grid 2x, 8 blocks/CU resident).
// Wave owns 8 nodes' edges (16-deep pipeline, scalarized descriptors).
// MFMA: wave = (row-group wv&1) x (col-group wv>>1); 2 n-tiles x 4 kt each.
// ---------------------------------------------------------------------------
__device__ __forceinline__ void tile_add(unsigned* p, float ax, float ay) {
    unsigned old = *p;
    *p = packbf(bflo(old) + ax, bfhi(old) + ay);
}

__global__ __launch_bounds__(256)
void conv1_fused_kernel(const ushort* __restrict__ xw1, const float* __restrict__ dinv,
                        const int* __restrict__ rowptr, const int2* __restrict__ ew,
                        const float* __restrict__ b1, const ushort* __restrict__ WT2,
                        ushort* __restrict__ xw2, int N)
{
    __shared__ ushort tile[16][33][8];   // 8.25 KiB
    __shared__ int srp[33];

    const int tid  = threadIdx.x;
    const int n0   = blockIdx.x * 32;
    const int nc   = min(32, N - n0);
    const int wv   = tid >> 6;
    const int lane = tid & 63;

    if (tid <= nc) srp[tid] = rowptr[n0 + tid];

    const float bb0 = b1[2 * lane];
    const float bb1 = b1[2 * lane + 1];
    const int  kg = lane >> 2;
    const int  jj = (2 * lane) & 7;
    unsigned* tbase = (unsigned*)&tile[kg][0][jj];   // row stride = 4 uints
    for (int r = wv; r < 32; r += 4) {
        float vx = 0.f, vy = 0.f;
        if (r < nc) {
            unsigned u = *(const unsigned*)(xw1 + (size_t)(n0 + r) * 128 + 2 * lane);
            float dt = dinv[n0 + r];
            float cc = dt * dt;
            vx = fmaf(bflo(u), cc, bb0);
            vy = fmaf(bfhi(u), cc, bb1);
        }
        tbase[r * 4] = packbf(vx, vy);
    }
    __syncthreads();

    const int nlo = wv * 8;
    if (nlo < nc) {
        const int nhi = min(nlo + 8, nc);
        const int e0 = srp[0];
        int i = srp[nlo] - e0;
        const int iend = srp[nhi] - e0;
        int cur = nlo;
        int nxt = srp[nlo + 1] - e0;
        float ax = 0.f, ay = 0.f;

        for (; i + 16 <= iend; i += 16) {
            const int ib = __builtin_amdgcn_readfirstlane(e0 + i);
            int2 d[16];
#pragma unroll
            for (int u = 0; u < 16; ++u) d[u] = ew[ib + u];
            unsigned v[16];
#pragma unroll
            for (int u = 0; u < 16; ++u)
                v[u] = *(const unsigned*)(xw1 + (size_t)d[u].x * 128 + 2 * lane);
#pragma unroll
            for (int u = 0; u < 16; ++u) {
                const int idx = i + u;
                while (idx >= nxt) {
                    tile_add(tbase + cur * 4, ax, ay);
                    ax = 0.f; ay = 0.f;
                    ++cur;
                    nxt = srp[cur + 1] - e0;
                }
                const float w = __int_as_float(d[u].y);
                ax = fmaf(bflo(v[u]), w, ax);
                ay = fmaf(bfhi(v[u]), w, ay);
            }
        }
        for (; i + 4 <= iend; i += 4) {
            const int ib = __builtin_amdgcn_readfirstlane(e0 + i);
            int2 d[4];
#pragma unroll
            for (int u = 0; u < 4; ++u) d[u] = ew[ib + u];
            unsigned v[4];
#pragma unroll
            for (int u = 0; u < 4; ++u)
                v[u] = *(const unsigned*)(xw1 + (size_t)d[u].x * 128 + 2 * lane);
#pragma unroll
            for (int u = 0; u < 4; ++u) {
                const int idx = i + u;
                while (idx >= nxt) {
                    tile_add(tbase + cur * 4, ax, ay);
                    ax = 0.f; ay = 0.f;
                    ++cur;
                    nxt = srp[cur + 1] - e0;
                }
                const float w = __int_as_float(d[u].y);
                ax = fmaf(bflo(v[u]), w, ax);
                ay = fmaf(bfhi(v[u]), w, ay);
            }
        }
        for (; i < iend; ++i) {
            int2 d = ew[e0 + i];
            unsigned v = *(const unsigned*)(xw1 + (size_t)d.x * 128 + 2 * lane);
            while (i >= nxt) {
                tile_add(tbase + cur * 4, ax, ay);
                ax = 0.f; ay = 0.f;
                ++cur;
                nxt = srp[cur + 1] - e0;
            }
            const float w = __int_as_float(d.y);
            ax = fmaf(bflo(v), w, ax);
            ay = fmaf(bfhi(v), w, ay);
        }
        tile_add(tbase + cur * 4, ax, ay);
    }
    __syncthreads();

    // ---- MFMA: 32 rows x 64 cols; wave = (rowg = wv&1) x (colg = wv>>1) ----
    const int lr = lane & 15;
    const int lk = lane >> 4;
    const int rowg = wv & 1;
    const int colg = wv >> 1;
    f32x4 acc[2];
    acc[0] = (f32x4){0.f, 0.f, 0.f, 0.f};
    acc[1] = (f32x4){0.f, 0.f, 0.f, 0.f};

    for (int kt = 0; kt < 4; ++kt) {
        short8 ah = *(const short8*)&tile[kt * 4 + lk][rowg * 16 + lr][0];
#pragma unroll
        for (int j = 0; j < 8; ++j) {
            ushort vv = (ushort)ah[j];
            ah[j] = (short)((vv & 0x8000u) ? 0 : vv);
        }
#pragma unroll
        for (int nn = 0; nn < 2; ++nn) {
            const int n = colg * 2 + nn;
            short8 bh = *(const short8*)(WT2 + (size_t)(n * 16 + lr) * 128 + kt * 32 + lk * 8);
            acc[nn] = __builtin_amdgcn_mfma_f32_16x16x32_bf16(bh, ah, acc[nn], 0, 0, 0);
        }
    }

    const int ml = rowg * 16 + lr;
    if (ml < nc) {
        const size_t m = (size_t)(n0 + ml);
#pragma unroll
        for (int nn = 0; nn < 2; ++nn) {
            const int n = colg * 2 + nn;
            uint2 u;
            u.x = (unsigned)f2bf(acc[nn][0]) | ((unsigned)f2bf(acc[nn][1]) << 16);
            u.y = (unsigned)f2bf(acc[nn][2]) | ((unsigned)f2bf(acc[nn][3]) << 16);
            *(uint2*)(xw2 + m * 64 + n * 16 + 4 * lk) = u;
        }
    }
}

// ---------------------------------------------------------------------------
// gather2_flat v3: 32 nodes/block; wave owns 8 nodes; 16/4/1 ladder.
// ---------------------------------------------------------------------------
__global__ __launch_bounds__(256)
void gather2_flat_kernel(const ushort* __restrict__ xw, const float* __restrict__ dinv,
                         const int* __restrict__ rowptr, const int2* __restrict__ ew,
                         const float* __restrict__ bias, ushort* __restrict__ out, int N)
{
    __shared__ int srp[33];

    const int tid  = threadIdx.x;
    const int n0   = blockIdx.x * 32;
    const int nc   = min(32, N - n0);
    const int wv   = tid >> 6;
    const int lane = tid & 63;

    if (tid <= nc) srp[tid] = rowptr[n0 + tid];
    __syncthreads();

    const int nlo = wv * 8;
    if (nlo >= nc) return;
    const int nhi = min(nlo + 8, nc);
    const float bl = bias[lane];

    int j = srp[nlo];
    const int jend = srp[nhi];
    int cur = nlo;
    int nxt = srp[nlo + 1];
    float acc = 0.f;

    auto flush = [&](int c, float a) {
        const size_t g = (size_t)(n0 + c);
        const float self = bf2f(xw[g * 64 + lane]);
        const float dt = dinv[g];
        out[g * 64 + lane] = f2bf(fmaf(self, dt * dt, a + bl));
    };

    for (; j + 16 <= jend; j += 16) {
        const int jb = __builtin_amdgcn_readfirstlane(j);
        int2 d[16];
#pragma unroll
        for (int u = 0; u < 16; ++u) d[u] = ew[jb + u];
        float v[16];
#pragma unroll
        for (int u = 0; u < 16; ++u) v[u] = bf2f(xw[(size_t)d[u].x * 64 + lane]);
#pragma unroll
        for (int u = 0; u < 16; ++u) {
            const int idx = j + u;
            while (idx >= nxt) {
                flush(cur, acc);
                acc = 0.f;
                ++cur;
                nxt = srp[cur + 1];
            }
            acc = fmaf(v[u], __int_as_float(d[u].y), acc);
        }
    }
    for (; j + 4 <= jend; j += 4) {
        const int jb = __builtin_amdgcn_readfirstlane(j);
        int2 d[4];
#pragma unroll
        for (int u = 0; u < 4; ++u) d[u] = ew[jb + u];
        float v[4];
#pragma unroll
        for (int u = 0; u < 4; ++u) v[u] = bf2f(xw[(size_t)d[u].x * 64 + lane]);
#pragma unroll
        for (int u = 0; u < 4; ++u) {
            const int idx = j + u;
            while (idx >= nxt) {
                flush(cur, acc);
                acc = 0.f;
                ++cur;
                nxt = srp[cur + 1];
            }
            acc = fmaf(v[u], __int_as_float(d[u].y), acc);
        }
    }
    for (; j < jend; ++j) {
        int2 d = ew[j];
        float v = bf2f(xw[(size_t)d.x * 64 + lane]);
        while (j >= nxt) {
            flush(cur, acc);
            acc = 0.f;
            ++cur;
            nxt = srp[cur + 1];
        }
        acc = fmaf(v, __int_as_float(d.y), acc);
    }
    flush(cur, acc);
    for (int c = cur + 1; c < nhi; ++c) flush(c, 0.f);
}

// ---------------------------------------------------------------------------
// logits[e] = dot(h2[a], h2[b]) over D=64 bf16. 4 lanes/edge, 2x uint4 each.
// ---------------------------------------------------------------------------
__global__ void score_kernel(const ushort* __restrict__ h, const int* __restrict__ ea,
                             const int* __restrict__ eb, float* __restrict__ out, int E)
{
    long long gid = (long long)blockIdx.x * blockDim.x + threadIdx.x;
    int e = (int)(gid >> 2);
    int l = (int)(gid & 3);
    if (e >= E) return;
    int a = ea[e], b = eb[e];
    const uint4* pa = (const uint4*)(h + (size_t)a * 64 + 16 * l);
    const uint4* pb = (const uint4*)(h + (size_t)b * 64 + 16 * l);
    uint4 ua0 = pa[0], ua1 = pa[1];
    uint4 ub0 = pb[0], ub1 = pb[1];
    float s;
    s  = bflo(ua0.x) * bflo(ub0.x) + bfhi(ua0.x) * bfhi(ub0.x);
    s += bflo(ua0.y) * bflo(ub0.y) + bfhi(ua0.y) * bfhi(ub0.y);
    s += bflo(ua0.z) * bflo(ub0.z) + bfhi(ua0.z) * bfhi(ub0.z);
    s += bflo(ua0.w) * bflo(ub0.w) + bfhi(ua0.w) * bfhi(ub0.w);
    s += bflo(ua1.x) * bflo(ub1.x) + bfhi(ua1.x) * bfhi(ub1.x);
    s += bflo(ua1.y) * bflo(ub1.y) + bfhi(ua1.y) * bfhi(ub1.y);
    s += bflo(ua1.z) * bflo(ub1.z) + bfhi(ua1.z) * bfhi(ub1.z);
    s += bflo(ua1.w) * bflo(ub1.w) + bfhi(ua1.w) * bfhi(ub1.w);
    s += __shfl_xor(s, 2);
    s += __shfl_xor(s, 1);
    if (l == 0) out[e] = s;
}

extern "C" void kernel_launch(void* const* d_in, const int* in_sizes, int n_in,
                              void* d_out, int out_size, void* d_ws, size_t ws_size,
                              hipStream_t stream)
{
    const float* x              = (const float*)d_in[0];
    const int*   edge_index     = (const int*)d_in[1];
    const int*   pos_edge_index = (const int*)d_in[2];
    const float* W_init         = (const float*)d_in[3];
    const float* b_init         = (const float*)d_in[4];
    const float* W1             = (const float*)d_in[5];
    const float* b1             = (const float*)d_in[6];
    const float* W2             = (const float*)d_in[7];
    const float* b2             = (const float*)d_in[8];
    float* out = (float*)d_out;

    const int N     = in_sizes[0] / 128;   // 100000
    const int Epred = in_sizes[1] / 2;     // 200000
    const int E     = in_sizes[2] / 2;     // 500000

    const int* src = pos_edge_index;
    const int* tgt = pos_edge_index + E;
    const int* ea  = edge_index;
    const int* eb  = edge_index + Epred;

    // ---- workspace ----
    int2*   ew   = (int2*)d_ws;                      // E
    ushort* regA = (ushort*)(ew + E);                // N*128   (xw1 — live through conv1_fused)
    ushort* regB = regA + (size_t)N * 128;           // N*128   (= two N*64 planes: xw2, h2)
    float*  dinv = (float*)(regB + (size_t)N * 128);
    int*   counts = (int*)(dinv + N);                // N
    int*   cursor = counts + N;                      // N
    int*   rowptr = cursor + N;                      // N+2
    int*   bsum   = rowptr + N + 2;                  // 256
    ushort* WTi = (ushort*)(((uintptr_t)(bsum + 256) + 15) & ~(uintptr_t)15);  // 128*128
    ushort* WT1 = WTi + 16384;                       // 128*128
    ushort* WT2 = WT1 + 16384;                       // 64*128

    ushort* xw1 = regA;
    ushort* xw2 = regB;                      // distinct from xw1 (R7 race lesson)
    ushort* h2  = regB + (size_t)N * 64;     // distinct from xw2 (gather2 reads xw2)

    const int BLK = 256;
    const int nb  = (N + 1023) / 1024;

    // ---- prep: zero counts+cursor, transpose all weights ----
    prep_kernel<<<(2 * N + BLK - 1) / BLK, BLK, 0, stream>>>(
        W_init, W1, W2, WTi, WT1, WT2, counts, 2 * N);

    // ---- CSR build ----
    hist_kernel<<<(E + BLK - 1) / BLK, BLK, 0, stream>>>(tgt, counts, E);
    scan1_kernel<<<nb, 256, 0, stream>>>(counts, rowptr, bsum, dinv, N);
    scan3_kernel<<<(N + BLK - 1) / BLK, BLK, 0, stream>>>(rowptr, bsum, N, E, nb);
    scatter_kernel<<<(E + BLK - 1) / BLK, BLK, 0, stream>>>(src, tgt, dinv, rowptr, cursor, ew, E);

    // ---- fused gemm0+gemm1: xw1 = bf16((x@Wi+bi)@W1) ----
    fused_gemm01_kernel<<<(N + 127) / 128, BLK, 0, stream>>>(x, WTi, WT1, b_init, xw1, N);

    // ---- conv1_fused: xw2 = bf16(relu(agg(xw1)+self+b1) @ W2) ----
    conv1_fused_kernel<<<(N + 31) / 32, BLK, 0, stream>>>(
        xw1, dinv, rowptr, ew, b1, WT2, xw2, N);

    // ---- gather2_flat: h2 = bf16(agg(xw2)+self+b2) ----
    gather2_flat_kernel<<<(N + 31) / 32, BLK, 0, stream>>>(
        xw2, dinv, rowptr, ew, b2, h2, N);

    // ---- scoring ----
    score_kernel<<<((long long)Epred * 4 + BLK - 1) / BLK, BLK, 0, stream>>>(
        h2, ea, eb, out, Epred);
}

// Round 14
// 164.108 us; speedup vs baseline: 1.0076x; 1.0076x over previous
//
#include <hip/hip_runtime.h>

// ---------------------------------------------------------------------------
// GCN link-prediction pipeline, R14 (= R13 with 4-byte packed edge
// descriptors: (src<<15) | bf16_no_sign(w). Halves ew traffic and halves
// descriptor VGPRs in the 16-deep gather pipelines).
//   fused01:     xw1 = bf16( (x @ W_init + b_init) @ W1 )
//   conv1_fused: xw2 = bf16( relu(gather(xw1)+self+b1) @ W2 )  [r1 in LDS]
//   gath2_flat:  h2 = bf16(gather(xw2)+self+b2)
//   score:       logits[e] = dot(h2[ea], h2[eb])
// ---------------------------------------------------------------------------

typedef __attribute__((ext_vector_type(8))) short short8;
typedef __attribute__((ext_vector_type(4))) float f32x4;

__device__ __forceinline__ ushort f2bf(float v) {
    unsigned u = __float_as_uint(v);
    return (ushort)((u + 0x7FFFu + ((u >> 16) & 1u)) >> 16);
}
__device__ __forceinline__ float bf2f(ushort b) {
    return __uint_as_float(((unsigned)b) << 16);
}
__device__ __forceinline__ float bflo(unsigned u) { return __uint_as_float(u << 16); }
__device__ __forceinline__ float bfhi(unsigned u) { return __uint_as_float(u & 0xFFFF0000u); }
__device__ __forceinline__ unsigned packbf(float x, float y) {
    return (unsigned)f2bf(x) | ((unsigned)f2bf(y) << 16);
}
__device__ __forceinline__ void split2(float v, ushort& h, ushort& l) {
    unsigned u = __float_as_uint(v);
    unsigned hb = (u + 0x7FFFu + ((u >> 16) & 1u)) & 0xFFFF0000u;
    h = (ushort)(hb >> 16);
    l = f2bf(v - __uint_as_float(hb));
}
// packed edge descriptor: src (17 bits) << 15 | bf16(w) without sign (15 bits)
__device__ __forceinline__ unsigned ed_src(unsigned p) { return p >> 15; }
__device__ __forceinline__ float    ed_w(unsigned p)   { return __uint_as_float((p & 0x7FFFu) << 16); }

// ---------------- prep: zero counts/cursor + all weight transposes ----------
__global__ void prep_kernel(const float* __restrict__ Wi, const float* __restrict__ W1,
                            const float* __restrict__ W2,
                            ushort* __restrict__ Ti, ushort* __restrict__ T1,
                            ushort* __restrict__ T2, int* __restrict__ zp, int ztot)
{
    int o = blockIdx.x * blockDim.x + threadIdx.x;
    if (o < ztot) zp[o] = 0;
    if (o < 16384) {
        int c = o >> 7, k = o & 127;
        Ti[o] = f2bf(Wi[(size_t)k * 128 + c]);
    } else if (o < 32768) {
        int p = o - 16384;
        int c = p >> 7, k = p & 127;
        T1[p] = f2bf(W1[(size_t)k * 128 + c]);
    } else if (o < 40960) {
        int p = o - 32768;
        int c = p >> 7, k = p & 127;
        T2[p] = f2bf(W2[(size_t)k * 64 + c]);
    }
}

// ---------------- CSR build ----------------
__global__ void hist_kernel(const int* __restrict__ tgt, int* __restrict__ counts, int e) {
    int i = blockIdx.x * blockDim.x + threadIdx.x;
    if (i < e) atomicAdd(&counts[tgt[i]], 1);
}
__global__ __launch_bounds__(256)
void scan1_kernel(const int* __restrict__ counts, int* __restrict__ rowptr,
                  int* __restrict__ bsum, float* __restrict__ dinv, int n)
{
    __shared__ int sdata[256];
    const int t = threadIdx.x;
    const int base = blockIdx.x * 1024 + t * 4;
    int v[4];
#pragma unroll
    for (int i = 0; i < 4; i++) v[i] = (base + i < n) ? counts[base + i] : 0;
#pragma unroll
    for (int i = 0; i < 4; i++)
        if (base + i < n) dinv[base + i] = 1.0f / sqrtf((float)(v[i] + 1));
    int tsum = v[0] + v[1] + v[2] + v[3];
    sdata[t] = tsum;
    __syncthreads();
    for (int off = 1; off < 256; off <<= 1) {
        int x = (t >= off) ? sdata[t - off] : 0;
        __syncthreads();
        if (t >= off) sdata[t] += x;
        __syncthreads();
    }
    if (t == 255) bsum[blockIdx.x] = sdata[255];
    int run = sdata[t] - tsum;
#pragma unroll
    for (int i = 0; i < 4; i++) {
        if (base + i < n) rowptr[base + i] = run;
        run += v[i];
    }
}
__global__ void scan3_kernel(int* __restrict__ rowptr, const int* __restrict__ bsum,
                             int n, int e_total, int nb)
{
    __shared__ int pre;
    const int k0 = (blockIdx.x * 256) >> 10;
    if (threadIdx.x == 0) {
        int s = 0;
        for (int k = 0; k < k0; ++k) s += bsum[k];
        pre = s;
    }
    __syncthreads();
    int i = blockIdx.x * 256 + threadIdx.x;
    if (i < n) rowptr[i] += pre;
    if (i == 0) rowptr[n] = e_total;
}
__global__ void scatter_kernel(const int* __restrict__ src, const int* __restrict__ tgt,
                               const float* __restrict__ dinv, const int* __restrict__ rowptr,
                               int* __restrict__ cursor, unsigned* __restrict__ ew, int e)
{
    int i = blockIdx.x * blockDim.x + threadIdx.x;
    if (i >= e) return;
    int s = src[i], t = tgt[i];
    int p = rowptr[t] + atomicAdd(&cursor[t], 1);
    const float w = dinv[s] * dinv[t];                    // > 0 always
    ew[p] = ((unsigned)s << 15) | ((unsigned)f2bf(w) & 0x7FFFu);
}

// ---------------------------------------------------------------------------
// Fused gemm0+gemm1 (unchanged from R11): xw1 = bf16((x @ Wi + bi) @ W1).
// ---------------------------------------------------------------------------
__global__ __launch_bounds__(256)
void fused_gemm01_kernel(const float* __restrict__ x,
                         const ushort* __restrict__ WTi, const ushort* __restrict__ WT1,
                         const float* __restrict__ bias, ushort* __restrict__ xw1, int M)
{
    __shared__ ushort raw[20480];                            // 40 KiB
    ushort (*H0)[128][8] = (ushort(*)[128][8])raw;           // 16 ks, 32 KiB
    ushort (*Ah)[128][8] = (ushort(*)[128][8])raw;           // aliases H0[0..4)
    ushort (*Al)[128][8] = (ushort(*)[128][8])(raw + 4096);  // aliases H0[4..8)
    ushort (*Bs)[128][8] = (ushort(*)[128][8])(raw + 16384); // 8 KiB

    const int tid = threadIdx.x;
    const int row0 = blockIdx.x * 128;
    const int wv = tid >> 6;
    const int l  = tid & 63;
    const int lr = l & 15;
    const int lk = l >> 4;

    f32x4 acc0[8], acc1[8];
#pragma unroll
    for (int n = 0; n < 8; ++n) {
        acc0[n] = (f32x4){0.f, 0.f, 0.f, 0.f};
        acc1[n] = (f32x4){0.f, 0.f, 0.f, 0.f};
    }

    for (int kk = 0; kk < 128; kk += 32) {
        {
            const int r  = tid >> 1;
            const int kh = tid & 1;
            const int gr = row0 + r;
            float f[16];
            if (gr < M) {
                const float4* p = (const float4*)(x + (size_t)gr * 128 + kk + kh * 16);
                float4 q0 = p[0], q1 = p[1], q2 = p[2], q3 = p[3];
                f[0]=q0.x; f[1]=q0.y; f[2]=q0.z; f[3]=q0.w;
                f[4]=q1.x; f[5]=q1.y; f[6]=q1.z; f[7]=q1.w;
                f[8]=q2.x; f[9]=q2.y; f[10]=q2.z; f[11]=q2.w;
                f[12]=q3.x; f[13]=q3.y; f[14]=q3.z; f[15]=q3.w;
            } else {
#pragma unroll
                for (int j = 0; j < 16; j++) f[j] = 0.f;
            }
#pragma unroll
            for (int uu = 0; uu < 2; ++uu) {
                short8 hv, lv;
#pragma unroll
                for (int j = 0; j < 8; ++j) {
                    ushort h, lo;
                    split2(f[8 * uu + j], h, lo);
                    hv[j] = (short)h; lv[j] = (short)lo;
                }
                *(short8*)&Ah[2 * kh + uu][r][0] = hv;
                *(short8*)&Al[2 * kh + uu][r][0] = lv;
            }
        }
        {
#pragma unroll
            for (int u = 0; u < 2; ++u) {
                const int unit = tid * 2 + u;
                const int c   = unit >> 2;
                const int kgl = unit & 3;
                *(short8*)&Bs[kgl][c][0] = *(const short8*)(WTi + (size_t)c * 128 + kk + 8 * kgl);
            }
        }
        __syncthreads();
        short8 ah0 = *(const short8*)&Ah[lk][wv * 32 + lr][0];
        short8 ah1 = *(const short8*)&Ah[lk][wv * 32 + 16 + lr][0];
        short8 al0 = *(const short8*)&Al[lk][wv * 32 + lr][0];
        short8 al1 = *(const short8*)&Al[lk][wv * 32 + 16 + lr][0];
#pragma unroll
        for (int n = 0; n < 8; ++n) {
            short8 bh = *(const short8*)&Bs[lk][n * 16 + lr][0];
            acc0[n] = __builtin_amdgcn_mfma_f32_16x16x32_bf16(bh, ah0, acc0[n], 0, 0, 0);
            acc1[n] = __builtin_amdgcn_mfma_f32_16x16x32_bf16(bh, ah1, acc1[n], 0, 0, 0);
            acc0[n] = __builtin_amdgcn_mfma_f32_16x16x32_bf16(bh, al0, acc0[n], 0, 0, 0);
            acc1[n] = __builtin_amdgcn_mfma_f32_16x16x32_bf16(bh, al1, acc1[n], 0, 0, 0);
        }
        __syncthreads();
    }

#pragma unroll
    for (int n = 0; n < 8; ++n) {
        const float4 b4 = *(const float4*)(bias + n * 16 + 4 * lk);
        const float bb[4] = {b4.x, b4.y, b4.z, b4.w};
        const int ks = 2 * n + (lk >> 1);
        const int jo = (lk & 1) * 4;
#pragma unroll
        for (int half = 0; half < 2; ++half) {
            const int m = wv * 32 + 16 * half + lr;
            unsigned hw[4];
#pragma unroll
            for (int r = 0; r < 4; ++r)
                hw[r] = f2bf((half ? acc1[n][r] : acc0[n][r]) + bb[r]);
            uint2 uh;
            uh.x = hw[0] | (hw[1] << 16);
            uh.y = hw[2] | (hw[3] << 16);
            *(uint2*)&H0[ks][m][jo] = uh;
        }
    }
    __syncthreads();

#pragma unroll
    for (int n = 0; n < 8; ++n) {
        acc0[n] = (f32x4){0.f, 0.f, 0.f, 0.f};
        acc1[n] = (f32x4){0.f, 0.f, 0.f, 0.f};
    }
    for (int kk = 0; kk < 4; ++kk) {
        {
#pragma unroll
            for (int u = 0; u < 2; ++u) {
                const int unit = tid * 2 + u;
                const int c   = unit >> 2;
                const int kgl = unit & 3;
                *(short8*)&Bs[kgl][c][0] = *(const short8*)(WT1 + (size_t)c * 128 + kk * 32 + 8 * kgl);
            }
        }
        __syncthreads();
        short8 a0 = *(const short8*)&H0[kk * 4 + lk][wv * 32 + lr][0];
        short8 a1 = *(const short8*)&H0[kk * 4 + lk][wv * 32 + 16 + lr][0];
#pragma unroll
        for (int n = 0; n < 8; ++n) {
            short8 bh = *(const short8*)&Bs[lk][n * 16 + lr][0];
            acc0[n] = __builtin_amdgcn_mfma_f32_16x16x32_bf16(bh, a0, acc0[n], 0, 0, 0);
            acc1[n] = __builtin_amdgcn_mfma_f32_16x16x32_bf16(bh, a1, acc1[n], 0, 0, 0);
        }
        __syncthreads();
    }

#pragma unroll
    for (int n = 0; n < 8; ++n) {
#pragma unroll
        for (int half = 0; half < 2; ++half) {
            const int m = row0 + wv * 32 + 16 * half + lr;
            if (m < M) {
                uint2 u;
                const f32x4 a = half ? acc1[n] : acc0[n];
                u.x = (unsigned)f2bf(a[0]) | ((unsigned)f2bf(a[1]) << 16);
                u.y = (unsigned)f2bf(a[2]) | ((unsigned)f2bf(a[3]) << 16);
                *(uint2*)(xw1 + (size_t)m * 128 + n * 16 + 4 * lk) = u;
            }
        }
    }
}

// ---------------------------------------------------------------------------
// conv1_fused v5: 32 nodes/block, 16-deep pipeline, 4B packed descriptors.
// ---------------------------------------------------------------------------
__device__ __forceinline__ void tile_add(unsigned* p, float ax, float ay) {
    unsigned old = *p;
    *p = packbf(bflo(old) + ax, bfhi(old) + ay);
}

__global__ __launch_bounds__(256)
void conv1_fused_kernel(const ushort* __restrict__ xw1, const float* __restrict__ dinv,
                        const int* __restrict__ rowptr, const unsigned* __restrict__ ew,
                        const float* __restrict__ b1, const ushort* __restrict__ WT2,
                        ushort* __restrict__ xw2, int N)
{
    __shared__ ushort tile[16][33][8];   // 8.25 KiB
    __shared__ int srp[33];

    const int tid  = threadIdx.x;
    const int n0   = blockIdx.x * 32;
    const int nc   = min(32, N - n0);
    const int wv   = tid >> 6;
    const int lane = tid & 63;

    if (tid <= nc) srp[tid] = rowptr[n0 + tid];

    const float bb0 = b1[2 * lane];
    const float bb1 = b1[2 * lane + 1];
    const int  kg = lane >> 2;
    const int  jj = (2 * lane) & 7;
    unsigned* tbase = (unsigned*)&tile[kg][0][jj];   // row stride = 4 uints
    for (int r = wv; r < 32; r += 4) {
        float vx = 0.f, vy = 0.f;
        if (r < nc) {
            unsigned u = *(const unsigned*)(xw1 + (size_t)(n0 + r) * 128 + 2 * lane);
            float dt = dinv[n0 + r];
            float cc = dt * dt;
            vx = fmaf(bflo(u), cc, bb0);
            vy = fmaf(bfhi(u), cc, bb1);
        }
        tbase[r * 4] = packbf(vx, vy);
    }
    __syncthreads();

    const int nlo = wv * 8;
    if (nlo < nc) {
        const int nhi = min(nlo + 8, nc);
        const int e0 = srp[0];
        int i = srp[nlo] - e0;
        const int iend = srp[nhi] - e0;
        int cur = nlo;
        int nxt = srp[nlo + 1] - e0;
        float ax = 0.f, ay = 0.f;

        for (; i + 16 <= iend; i += 16) {
            const int ib = __builtin_amdgcn_readfirstlane(e0 + i);
            unsigned d[16];
#pragma unroll
            for (int u = 0; u < 16; ++u) d[u] = ew[ib + u];
            unsigned v[16];
#pragma unroll
            for (int u = 0; u < 16; ++u)
                v[u] = *(const unsigned*)(xw1 + (size_t)ed_src(d[u]) * 128 + 2 * lane);
#pragma unroll
            for (int u = 0; u < 16; ++u) {
                const int idx = i + u;
                while (idx >= nxt) {
                    tile_add(tbase + cur * 4, ax, ay);
                    ax = 0.f; ay = 0.f;
                    ++cur;
                    nxt = srp[cur + 1] - e0;
                }
                const float w = ed_w(d[u]);
                ax = fmaf(bflo(v[u]), w, ax);
                ay = fmaf(bfhi(v[u]), w, ay);
            }
        }
        for (; i + 4 <= iend; i += 4) {
            const int ib = __builtin_amdgcn_readfirstlane(e0 + i);
            unsigned d[4];
#pragma unroll
            for (int u = 0; u < 4; ++u) d[u] = ew[ib + u];
            unsigned v[4];
#pragma unroll
            for (int u = 0; u < 4; ++u)
                v[u] = *(const unsigned*)(xw1 + (size_t)ed_src(d[u]) * 128 + 2 * lane);
#pragma unroll
            for (int u = 0; u < 4; ++u) {
                const int idx = i + u;
                while (idx >= nxt) {
                    tile_add(tbase + cur * 4, ax, ay);
                    ax = 0.f; ay = 0.f;
                    ++cur;
                    nxt = srp[cur + 1] - e0;
                }
                const float w = ed_w(d[u]);
                ax = fmaf(bflo(v[u]), w, ax);
                ay = fmaf(bfhi(v[u]), w, ay);
            }
        }
        for (; i < iend; ++i) {
            unsigned d = ew[e0 + i];
            unsigned v = *(const unsigned*)(xw1 + (size_t)ed_src(d) * 128 + 2 * lane);
            while (i >= nxt) {
                tile_add(tbase + cur * 4, ax, ay);
                ax = 0.f; ay = 0.f;
                ++cur;
                nxt = srp[cur + 1] - e0;
            }
            const float w = ed_w(d);
            ax = fmaf(bflo(v), w, ax);
            ay = fmaf(bfhi(v), w, ay);
        }
        tile_add(tbase + cur * 4, ax, ay);
    }
    __syncthreads();

    // ---- MFMA: 32 rows x 64 cols; wave = (rowg = wv&1) x (colg = wv>>1) ----
    const int lr = lane & 15;
    const int lk = lane >> 4;
    const int rowg = wv & 1;
    const int colg = wv >> 1;
    f32x4 acc[2];
    acc[0] = (f32x4){0.f, 0.f, 0.f, 0.f};
    acc[1] = (f32x4){0.f, 0.f, 0.f, 0.f};

    for (int kt = 0; kt < 4; ++kt) {
        short8 ah = *(const short8*)&tile[kt * 4 + lk][rowg * 16 + lr][0];
#pragma unroll
        for (int j = 0; j < 8; ++j) {
            ushort vv = (ushort)ah[j];
            ah[j] = (short)((vv & 0x8000u) ? 0 : vv);
        }
#pragma unroll
        for (int nn = 0; nn < 2; ++nn) {
            const int n = colg * 2 + nn;
            short8 bh = *(const short8*)(WT2 + (size_t)(n * 16 + lr) * 128 + kt * 32 + lk * 8);
            acc[nn] = __builtin_amdgcn_mfma_f32_16x16x32_bf16(bh, ah, acc[nn], 0, 0, 0);
        }
    }

    const int ml = rowg * 16 + lr;
    if (ml < nc) {
        const size_t m = (size_t)(n0 + ml);
#pragma unroll
        for (int nn = 0; nn < 2; ++nn) {
            const int n = colg * 2 + nn;
            uint2 u;
            u.x = (unsigned)f2bf(acc[nn][0]) | ((unsigned)f2bf(acc[nn][1]) << 16);
            u.y = (unsigned)f2bf(acc[nn][2]) | ((unsigned)f2bf(acc[nn][3]) << 16);
            *(uint2*)(xw2 + m * 64 + n * 16 + 4 * lk) = u;
        }
    }
}

// ---------------------------------------------------------------------------
// gather2_flat v4: 32 nodes/block, 16-deep, 4B packed descriptors.
// ---------------------------------------------------------------------------
__global__ __launch_bounds__(256)
void gather2_flat_kernel(const ushort* __restrict__ xw, const float* __restrict__ dinv,
                         const int* __restrict__ rowptr, const unsigned* __restrict__ ew,
                         const float* __restrict__ bias, ushort* __restrict__ out, int N)
{
    __shared__ int srp[33];

    const int tid  = threadIdx.x;
    const int n0   = blockIdx.x * 32;
    const int nc   = min(32, N - n0);
    const int wv   = tid >> 6;
    const int lane = tid & 63;

    if (tid <= nc) srp[tid] = rowptr[n0 + tid];
    __syncthreads();

    const int nlo = wv * 8;
    if (nlo >= nc) return;
    const int nhi = min(nlo + 8, nc);
    const float bl = bias[lane];

    int j = srp[nlo];
    const int jend = srp[nhi];
    int cur = nlo;
    int nxt = srp[nlo + 1];
    float acc = 0.f;

    auto flush = [&](int c, float a) {
        const size_t g = (size_t)(n0 + c);
        const float self = bf2f(xw[g * 64 + lane]);
        const float dt = dinv[g];
        out[g * 64 + lane] = f2bf(fmaf(self, dt * dt, a + bl));
    };

    for (; j + 16 <= jend; j += 16) {
        const int jb = __builtin_amdgcn_readfirstlane(j);
        unsigned d[16];
#pragma unroll
        for (int u = 0; u < 16; ++u) d[u] = ew[jb + u];
        float v[16];
#pragma unroll
        for (int u = 0; u < 16; ++u) v[u] = bf2f(xw[(size_t)ed_src(d[u]) * 64 + lane]);
#pragma unroll
        for (int u = 0; u < 16; ++u) {
            const int idx = j + u;
            while (idx >= nxt) {
                flush(cur, acc);
                acc = 0.f;
                ++cur;
                nxt = srp[cur + 1];
            }
            acc = fmaf(v[u], ed_w(d[u]), acc);
        }
    }
    for (; j + 4 <= jend; j += 4) {
        const int jb = __builtin_amdgcn_readfirstlane(j);
        unsigned d[4];
#pragma unroll
        for (int u = 0; u < 4; ++u) d[u] = ew[jb + u];
        float v[4];
#pragma unroll
        for (int u = 0; u < 4; ++u) v[u] = bf2f(xw[(size_t)ed_src(d[u]) * 64 + lane]);
#pragma unroll
        for (int u = 0; u < 4; ++u) {
            const int idx = j + u;
            while (idx >= nxt) {
                flush(cur, acc);
                acc = 0.f;
                ++cur;
                nxt = srp[cur + 1];
            }
            acc = fmaf(v[u], ed_w(d[u]), acc);
        }
    }
    for (; j < jend; ++j) {
        unsigned d = ew[j];
        float v = bf2f(xw[(size_t)ed_src(d) * 64 + lane]);
        while (j >= nxt) {
            flush(cur, acc);
            acc = 0.f;
            ++cur;
            nxt = srp[cur + 1];
        }
        acc = fmaf(v, ed_w(d), acc);
    }
    flush(cur, acc);
    for (int c = cur + 1; c < nhi; ++c) flush(c, 0.f);
}

// ---------------------------------------------------------------------------
// logits[e] = dot(h2[a], h2[b]) over D=64 bf16. 4 lanes/edge, 2x uint4 each.
// ---------------------------------------------------------------------------
__global__ void score_kernel(const ushort* __restrict__ h, const int* __restrict__ ea,
                             const int* __restrict__ eb, float* __restrict__ out, int E)
{
    long long gid = (long long)blockIdx.x * blockDim.x + threadIdx.x;
    int e = (int)(gid >> 2);
    int l = (int)(gid & 3);
    if (e >= E) return;
    int a = ea[e], b = eb[e];
    const uint4* pa = (const uint4*)(h + (size_t)a * 64 + 16 * l);
    const uint4* pb = (const uint4*)(h + (size_t)b * 64 + 16 * l);
    uint4 ua0 = pa[0], ua1 = pa[1];
    uint4 ub0 = pb[0], ub1 = pb[1];
    float s;
    s  = bflo(ua0.x) * bflo(ub0.x) + bfhi(ua0.x) * bfhi(ub0.x);
    s += bflo(ua0.y) * bflo(ub0.y) + bfhi(ua0.y) * bfhi(ub0.y);
    s += bflo(ua0.z) * bflo(ub0.z) + bfhi(ua0.z) * bfhi(ub0.z);
    s += bflo(ua0.w) * bflo(ub0.w) + bfhi(ua0.w) * bfhi(ub0.w);
    s += bflo(ua1.x) * bflo(ub1.x) + bfhi(ua1.x) * bfhi(ub1.x);
    s += bflo(ua1.y) * bflo(ub1.y) + bfhi(ua1.y) * bfhi(ub1.y);
    s += bflo(ua1.z) * bflo(ub1.z) + bfhi(ua1.z) * bfhi(ub1.z);
    s += bflo(ua1.w) * bflo(ub1.w) + bfhi(ua1.w) * bfhi(ub1.w);
    s += __shfl_xor(s, 2);
    s += __shfl_xor(s, 1);
    if (l == 0) out[e] = s;
}

extern "C" void kernel_launch(void* const* d_in, const int* in_sizes, int n_in,
                              void* d_out, int out_size, void* d_ws, size_t ws_size,
                              hipStream_t stream)
{
    const float* x              = (const float*)d_in[0];
    const int*   edge_index     = (const int*)d_in[1];
    const int*   pos_edge_index = (const int*)d_in[2];
    const float* W_init         = (const float*)d_in[3];
    const float* b_init         = (const float*)d_in[4];
    const float* W1             = (const float*)d_in[5];
    const float* b1             = (const float*)d_in[6];
    const float* W2             = (const float*)d_in[7];
    const float* b2             = (const float*)d_in[8];
    float* out = (float*)d_out;

    const int N     = in_sizes[0] / 128;   // 100000
    const int Epred = in_sizes[1] / 2;     // 200000
    const int E     = in_sizes[2] / 2;     // 500000

    const int* src = pos_edge_index;
    const int* tgt = pos_edge_index + E;
    const int* ea  = edge_index;
    const int* eb  = edge_index + Epred;

    // ---- workspace ----
    unsigned* ew  = (unsigned*)d_ws;                 // E (packed 4B descriptors)
    ushort* regA = (ushort*)(ew + E);                // N*128   (xw1 — live through conv1_fused)
    ushort* regB = regA + (size_t)N * 128;           // N*128   (= two N*64 planes: xw2, h2)
    float*  dinv = (float*)(regB + (size_t)N * 128);
    int*   counts = (int*)(dinv + N);                // N
    int*   cursor = counts + N;                      // N
    int*   rowptr = cursor + N;                      // N+2
    int*   bsum   = rowptr + N + 2;                  // 256
    ushort* WTi = (ushort*)(((uintptr_t)(bsum + 256) + 15) & ~(uintptr_t)15);  // 128*128
    ushort* WT1 = WTi + 16384;                       // 128*128
    ushort* WT2 = WT1 + 16384;                       // 64*128

    ushort* xw1 = regA;
    ushort* xw2 = regB;                      // distinct from xw1 (R7 race lesson)
    ushort* h2  = regB + (size_t)N * 64;     // distinct from xw2 (gather2 reads xw2)

    const int BLK = 256;
    const int nb  = (N + 1023) / 1024;

    // ---- prep: zero counts+cursor, transpose all weights ----
    prep_kernel<<<(2 * N + BLK - 1) / BLK, BLK, 0, stream>>>(
        W_init, W1, W2, WTi, WT1, WT2, counts, 2 * N);

    // ---- CSR build ----
    hist_kernel<<<(E + BLK - 1) / BLK, BLK, 0, stream>>>(tgt, counts, E);
    scan1_kernel<<<nb, 256, 0, stream>>>(counts, rowptr, bsum, dinv, N);
    scan3_kernel<<<(N + BLK - 1) / BLK, BLK, 0, stream>>>(rowptr, bsum, N, E, nb);
    scatter_kernel<<<(E + BLK - 1) / BLK, BLK, 0, stream>>>(src, tgt, dinv, rowptr, cursor, ew, E);

    // ---- fused gemm0+gemm1: xw1 = bf16((x@Wi+bi)@W1) ----
    fused_gemm01_kernel<<<(N + 127) / 128, BLK, 0, stream>>>(x, WTi, WT1, b_init, xw1, N);

    // ---- conv1_fused: xw2 = bf16(relu(agg(xw1)+self+b1) @ W2) ----
    conv1_fused_kernel<<<(N + 31) / 32, BLK, 0, stream>>>(
        xw1, dinv, rowptr, ew, b1, WT2, xw2, N);

    // ---- gather2_flat: h2 = bf16(agg(xw2)+self+b2) ----
    gather2_flat_kernel<<<(N + 31) / 32, BLK, 0, stream>>>(
        xw2, dinv, rowptr, ew, b2, h2, N);

    // ---- scoring ----
    score_kernel<<<((long long)Epred * 4 + BLK - 1) / BLK, BLK, 0, stream>>>(
        h2, ea, eb, out, Epred);
}